// Round 4
// baseline (244.457 us; speedup 1.0000x reference)
//
#include <hip/hip_runtime.h>
#include <math.h>

#define D_MODEL 256
#define NHEADS 8
#define HDIM 32
#define BATCH 8
#define SEQL 4096
#define EPS 1e-6f

typedef _Float16 f16;
typedef _Float16 f16x4 __attribute__((ext_vector_type(4)));
typedef _Float16 f16x8 __attribute__((ext_vector_type(8)));
typedef float f32x4 __attribute__((ext_vector_type(4)));

__device__ __forceinline__ float elu1(float x) {
    return x > 0.f ? x + 1.f : __expf(x);
}

// ---------------------------------------------------------------------------
// prep: convert 4 weight mats to fp16.  Stage-1 weights row-permuted to
// head-major output channels (o' = h*32+kd <- o = kd*8+h); Wm column-permuted
// to accept head-major input.  Stage-1 biases permuted (fp32).
// ---------------------------------------------------------------------------
__global__ void prep_kernel(const float* __restrict__ Wq, const float* __restrict__ Wk,
                            const float* __restrict__ Wv, const float* __restrict__ Wm,
                            const float* __restrict__ bq, const float* __restrict__ bk,
                            const float* __restrict__ bv,
                            f16* __restrict__ w16, float* __restrict__ bperm) {
    if (blockIdx.x < 1024) {
        int idx = blockIdx.x * 256 + threadIdx.x;
        int mat = idx >> 16, r = (idx >> 8) & 255, c = idx & 255;
        const float* W = (mat == 0) ? Wq : (mat == 1) ? Wk : (mat == 2) ? Wv : Wm;
        float v;
        if (mat < 3) v = W[(size_t)(((r & 31) << 3) + (r >> 5)) * 256 + c];
        else         v = W[(size_t)r * 256 + (((c & 31) << 3) + (c >> 5))];
        w16[idx] = (f16)v;
    } else {
        int t = threadIdx.x;
        bperm[0 * 256 + t] = bq[((t & 31) << 3) + (t >> 5)];
        bperm[1 * 256 + t] = bk[((t & 31) << 3) + (t >> 5)];
        bperm[2 * 256 + t] = bv[((t & 31) << 3) + (t >> 5)];
    }
}

__global__ void zero_kernel(float* __restrict__ p, int n) {
    int i = blockIdx.x * blockDim.x + threadIdx.x;
    if (i < n) p[i] = 0.f;
}

// ---------------------------------------------------------------------------
// Stage-1 GEMM: Y[b][l][o'] = fp16( sum_i W16[o'][i] * X[b][i][l] + bperm[o'] )
// M-tile 64 (grid.y=4) -> acc only 32 AGPR/thread -> ~4 waves/SIMD.
// Software-pipelined: double-buffered Bs (1 barrier/iter); X(k+1) float4s and
// W(k+1) fragments issued at top of iter k, consumed at bottom / next iter.
// ---------------------------------------------------------------------------
#define BSTR 40  // Bs row stride in halves: 16B rows, ~2-way banks
__global__ __launch_bounds__(256, 4) void gemm_stage1(
    const float* __restrict__ Xq, const float* __restrict__ Xk, const float* __restrict__ Xv,
    const f16* __restrict__ w16, const float* __restrict__ bperm,
    f16* __restrict__ yq, f16* __restrict__ yk, f16* __restrict__ yv) {
    __shared__ __align__(16) char smem[20480];
    f16* BsBuf[2] = {(f16*)smem, (f16*)smem + 128 * BSTR};  // 2 x 10240 B
    f16* Cb = (f16*)smem;  // [128][72] epilogue bounce (aliases Bs)

    const int z = blockIdx.z;
    const int which = z >> 3;
    const int b = z & 7;
    const float* X = (which == 0) ? Xq : (which == 1) ? Xk : Xv;
    const f16* W = w16 + which * 65536;
    f16* Y = (which == 0) ? yq : (which == 1) ? yk : yv;
    const float* bp = bperm + which * 256;

    const int l0 = blockIdx.x * 128;
    const int m0 = blockIdx.y * 64;
    const int tid = threadIdx.x;
    const int wave = tid >> 6, lane = tid & 63;
    const int wm = wave >> 1, wn = wave & 1;
    const int ln = lane & 15, quad = lane >> 4;
    const int bp8 = tid & 7;    // i-quad: i_local = 4*bp8 + r
    const int bg = tid >> 3;    // l-quad: l_local = 4*bg + j

    const float* Xbase = X + ((size_t)b * D_MODEL + 4 * bp8) * SEQL + l0 + 4 * bg;
    const f16* Wbase0 = W + (size_t)(m0 + wm * 32 + 0 * 16 + ln) * 256 + quad * 8;
    const f16* Wbase1 = W + (size_t)(m0 + wm * 32 + 1 * 16 + ln) * 256 + quad * 8;

    float4 xr[4];
    f16x8 af[2][2];

#define LOADX(K0) do { \
        const float* xb_ = Xbase + (size_t)(K0) * SEQL; \
        xr[0] = *(const float4*)(xb_ + 0 * SEQL); \
        xr[1] = *(const float4*)(xb_ + 1 * SEQL); \
        xr[2] = *(const float4*)(xb_ + 2 * SEQL); \
        xr[3] = *(const float4*)(xb_ + 3 * SEQL); \
    } while (0)

#define STOREB(BUF) do { \
        f16* Bsb_ = BsBuf[BUF]; \
        f16x4 w_; \
        w_[0] = (f16)xr[0].x; w_[1] = (f16)xr[1].x; w_[2] = (f16)xr[2].x; w_[3] = (f16)xr[3].x; \
        *(f16x4*)&Bsb_[(4 * bg + 0) * BSTR + 4 * bp8] = w_; \
        w_[0] = (f16)xr[0].y; w_[1] = (f16)xr[1].y; w_[2] = (f16)xr[2].y; w_[3] = (f16)xr[3].y; \
        *(f16x4*)&Bsb_[(4 * bg + 1) * BSTR + 4 * bp8] = w_; \
        w_[0] = (f16)xr[0].z; w_[1] = (f16)xr[1].z; w_[2] = (f16)xr[2].z; w_[3] = (f16)xr[3].z; \
        *(f16x4*)&Bsb_[(4 * bg + 2) * BSTR + 4 * bp8] = w_; \
        w_[0] = (f16)xr[0].w; w_[1] = (f16)xr[1].w; w_[2] = (f16)xr[2].w; w_[3] = (f16)xr[3].w; \
        *(f16x4*)&Bsb_[(4 * bg + 3) * BSTR + 4 * bp8] = w_; \
    } while (0)

    f32x4 acc[2][4];
#pragma unroll
    for (int mf = 0; mf < 2; ++mf)
#pragma unroll
        for (int nf = 0; nf < 4; ++nf)
#pragma unroll
            for (int r = 0; r < 4; ++r) acc[mf][nf][r] = 0.f;

    // prologue: stage k0=0, prefetch W(0)
    LOADX(0);
    af[0][0] = *(const f16x8*)(Wbase0 + 0);
    af[0][1] = *(const f16x8*)(Wbase1 + 0);
    STOREB(0);
    __syncthreads();

#pragma unroll
    for (int it = 0; it < 8; ++it) {
        const int k0 = it * 32;
        const int cur = it & 1, nxt = cur ^ 1;
        if (it < 7) {
            LOADX(k0 + 32);  // global loads in flight across the MFMA phase
            af[nxt][0] = *(const f16x8*)(Wbase0 + k0 + 32);
            af[nxt][1] = *(const f16x8*)(Wbase1 + k0 + 32);
        }
        f16x8 bf[4];
        const f16* Bsc = BsBuf[cur];
#pragma unroll
        for (int nf = 0; nf < 4; ++nf)
            bf[nf] = *(const f16x8*)&Bsc[(wn * 64 + nf * 16 + ln) * BSTR + quad * 8];
#pragma unroll
        for (int mf = 0; mf < 2; ++mf)
#pragma unroll
            for (int nf = 0; nf < 4; ++nf)
                acc[mf][nf] = __builtin_amdgcn_mfma_f32_16x16x32_f16(af[cur][mf], bf[nf], acc[mf][nf], 0, 0, 0);
        if (it < 7) STOREB(nxt);
        __syncthreads();
    }

    // epilogue: bias, bounce through LDS as [l][o], coalesced fp16 store
    float bv_[2][4];
#pragma unroll
    for (int mf = 0; mf < 2; ++mf)
#pragma unroll
        for (int r = 0; r < 4; ++r)
            bv_[mf][r] = bp[m0 + wm * 32 + mf * 16 + quad * 4 + r];
#pragma unroll
    for (int mf = 0; mf < 2; ++mf)
#pragma unroll
        for (int nf = 0; nf < 4; ++nf) {
            const int olocal = wm * 32 + mf * 16 + quad * 4;
            const int llocal = wn * 64 + nf * 16 + ln;
            f16x4 w;
#pragma unroll
            for (int r = 0; r < 4; ++r) w[r] = (f16)(acc[mf][nf][r] + bv_[mf][r]);
            *(f16x4*)&Cb[llocal * 72 + olocal] = w;
        }
    __syncthreads();
    {
        const int l = tid >> 1, half = tid & 1;
        f16* yr = Y + ((size_t)(b * SEQL + l0 + l)) * 256 + m0 + half * 32;
#pragma unroll
        for (int u = 0; u < 4; ++u)
            *(f16x8*)(yr + u * 8) = *(const f16x8*)&Cb[l * 72 + half * 32 + u * 8];
    }
}

// ---------------------------------------------------------------------------
// KV[b][h][qd][kd] = sum_l elu1(k'[l][kd]) * v'[l][qd];  ksum likewise.
// inputs fp16 [b][l][h*32+d].  grid (16 splits, 64 bh), 256 threads.
// ---------------------------------------------------------------------------
__global__ __launch_bounds__(256) void kv_kernel(
    const f16* __restrict__ kp, const f16* __restrict__ vp,
    float* __restrict__ KV, float* __restrict__ ksum) {
    const int bh = blockIdx.y;
    const int b = bh >> 3, h = bh & 7;
    const int lbase = blockIdx.x * (SEQL / 16);
    __shared__ float ks[64][33];
    __shared__ float vs[64][33];
    const int t = threadIdx.x;
    const int lrow = t >> 2, seg = t & 3;
    const int kd = t & 31, qg = t >> 5;
    float a0 = 0.f, a1 = 0.f, a2 = 0.f, a3 = 0.f, ss = 0.f;
    for (int lc = 0; lc < SEQL / 16; lc += 64) {
        __syncthreads();
        const size_t off = ((size_t)(b * SEQL + lbase + lc + lrow)) * 256 + h * 32 + seg * 8;
        f16x8 k8 = *(const f16x8*)(kp + off);
        f16x8 v8 = *(const f16x8*)(vp + off);
#pragma unroll
        for (int j = 0; j < 8; ++j) {
            ks[lrow][seg * 8 + j] = elu1((float)k8[j]);
            vs[lrow][seg * 8 + j] = (float)v8[j];
        }
        __syncthreads();
#pragma unroll 8
        for (int li = 0; li < 64; ++li) {
            const float kk = ks[li][kd];
            ss += kk;
            a0 += kk * vs[li][qg * 4 + 0];
            a1 += kk * vs[li][qg * 4 + 1];
            a2 += kk * vs[li][qg * 4 + 2];
            a3 += kk * vs[li][qg * 4 + 3];
        }
    }
    float* KVb = KV + (size_t)(b * NHEADS + h) * HDIM * HDIM;
    atomicAdd(&KVb[(qg * 4 + 0) * HDIM + kd], a0);
    atomicAdd(&KVb[(qg * 4 + 1) * HDIM + kd], a1);
    atomicAdd(&KVb[(qg * 4 + 2) * HDIM + kd], a2);
    atomicAdd(&KVb[(qg * 4 + 3) * HDIM + kd], a3);
    if (qg == 0) atomicAdd(&ksum[(size_t)(b * NHEADS + h) * HDIM + kd], ss);
}

// ---------------------------------------------------------------------------
// Fused attention + output projection (unchanged from R3).
// ---------------------------------------------------------------------------
__global__ __launch_bounds__(256) void attn_out_kernel(
    const f16* __restrict__ qp, const float* __restrict__ KV,
    const float* __restrict__ ksum, const f16* __restrict__ wm16,
    const float* __restrict__ bm, float* __restrict__ out) {
    __shared__ __align__(16) f16 xs[64 * 264];        // 33792 B
    __shared__ __align__(16) f16 Baug[8 * 48 * 40];   // 30720 B
    __shared__ float dens[8][64];                     // 2048 B
    const int b = blockIdx.y;
    const int l0 = blockIdx.x * 64;
    const int t = threadIdx.x;
    const int wave = t >> 6, lane = t & 63;
    const int ln = lane & 15, quad = lane >> 4;

    {
        const int h = t >> 5, qd = t & 31;
        const float* kvp = KV + ((size_t)(b * NHEADS + h) * HDIM + qd) * HDIM;
        f16* dst = &Baug[(h * 48 + qd) * 40];
#pragma unroll
        for (int i = 0; i < 32; i += 4) {
            float4 a = *(const float4*)(kvp + i);
            f16x4 w4;
            w4[0] = (f16)a.x; w4[1] = (f16)a.y; w4[2] = (f16)a.z; w4[3] = (f16)a.w;
            *(f16x4*)(dst + i) = w4;
        }
        Baug[(h * 48 + 32) * 40 + qd] = (f16)ksum[(size_t)(b * NHEADS + h) * HDIM + qd];
    }
    {
        const int row = t & 63, cg = t >> 6;
        const f16* qr = qp + ((size_t)(b * SEQL + l0 + row)) * 256 + cg * 64;
        f16* dst = &xs[row * 264 + cg * 64];
#pragma unroll
        for (int u = 0; u < 64; u += 8) {
            f16x8 v = *(const f16x8*)(qr + u);
            f16x8 w;
#pragma unroll
            for (int j = 0; j < 8; ++j) w[j] = (f16)elu1((float)v[j]);
            *(f16x8*)(dst + u) = w;
        }
    }
    __syncthreads();
#pragma unroll
    for (int hh = 0; hh < 2; ++hh) {
        const int h = wave * 2 + hh;
        f16x8 a_s[4], b_s[3];
#pragma unroll
        for (int mf = 0; mf < 4; ++mf)
            a_s[mf] = *(const f16x8*)&xs[(mf * 16 + ln) * 264 + h * 32 + quad * 8];
#pragma unroll
        for (int nf = 0; nf < 3; ++nf)
            b_s[nf] = *(const f16x8*)&Baug[(h * 48 + nf * 16 + ln) * 40 + quad * 8];
        f32x4 C[4][3];
#pragma unroll
        for (int mf = 0; mf < 4; ++mf)
#pragma unroll
            for (int nf = 0; nf < 3; ++nf) {
#pragma unroll
                for (int r = 0; r < 4; ++r) C[mf][nf][r] = 0.f;
                C[mf][nf] = __builtin_amdgcn_mfma_f32_16x16x32_f16(a_s[mf], b_s[nf], C[mf][nf], 0, 0, 0);
            }
        if (ln == 0) {
#pragma unroll
            for (int mf = 0; mf < 4; ++mf)
#pragma unroll
                for (int r = 0; r < 4; ++r)
                    dens[h][mf * 16 + quad * 4 + r] = C[mf][2][r];
        }
        __syncthreads();
#pragma unroll
        for (int mf = 0; mf < 4; ++mf)
#pragma unroll
            for (int r = 0; r < 4; ++r) {
                const int l = mf * 16 + quad * 4 + r;
                const float rd = __builtin_amdgcn_rcpf(dens[h][l] + EPS);
#pragma unroll
                for (int nf = 0; nf < 2; ++nf)
                    xs[l * 264 + h * 32 + nf * 16 + ln] = (f16)(C[mf][nf][r] * rd);
            }
        __syncthreads();
    }
    f32x4 acc[4][4];
#pragma unroll
    for (int mf = 0; mf < 4; ++mf)
#pragma unroll
        for (int nf = 0; nf < 4; ++nf)
#pragma unroll
            for (int r = 0; r < 4; ++r) acc[mf][nf][r] = 0.f;
    for (int k0 = 0; k0 < D_MODEL; k0 += 32) {
        f16x8 af[4], bf[4];
#pragma unroll
        for (int mf = 0; mf < 4; ++mf)
            af[mf] = *(const f16x8*)(wm16 + (size_t)(wave * 64 + mf * 16 + ln) * 256 + k0 + quad * 8);
#pragma unroll
        for (int nf = 0; nf < 4; ++nf)
            bf[nf] = *(const f16x8*)&xs[(nf * 16 + ln) * 264 + k0 + quad * 8];
#pragma unroll
        for (int mf = 0; mf < 4; ++mf)
#pragma unroll
            for (int nf = 0; nf < 4; ++nf)
                acc[mf][nf] = __builtin_amdgcn_mfma_f32_16x16x32_f16(af[mf], bf[nf], acc[mf][nf], 0, 0, 0);
    }
#pragma unroll
    for (int mf = 0; mf < 4; ++mf) {
        const int o = wave * 64 + mf * 16 + quad * 4;
#pragma unroll
        for (int r = 0; r < 4; ++r) {
            const float bb = bm[o + r];
            float* op = out + ((size_t)(b * D_MODEL + o + r)) * SEQL + l0;
#pragma unroll
            for (int nf = 0; nf < 4; ++nf)
                op[nf * 16 + ln] = acc[mf][nf][r] + bb;
        }
    }
}

// ---------------------------------------------------------------------------
extern "C" void kernel_launch(void* const* d_in, const int* in_sizes, int n_in,
                              void* d_out, int out_size, void* d_ws, size_t ws_size,
                              hipStream_t stream) {
    const float* query = (const float*)d_in[0];
    const float* key_  = (const float*)d_in[1];
    const float* value = (const float*)d_in[2];
    const float* Wq = (const float*)d_in[3];
    const float* bq = (const float*)d_in[4];
    const float* Wk = (const float*)d_in[5];
    const float* bk = (const float*)d_in[6];
    const float* Wv = (const float*)d_in[7];
    const float* bv = (const float*)d_in[8];
    const float* Wm = (const float*)d_in[9];
    const float* bm = (const float*)d_in[10];

    char* w = (char*)d_ws;
    f16*   w16   = (f16*)w;                       // 4*65536 halves = 512 KB
    float* bperm = (float*)(w + 524288);          // 768 floats
    float* KV    = (float*)(w + 528384);          // 65536 floats
    float* ksum  = (float*)(w + 790528);          // 2048 floats
    f16*   qp    = (f16*)(w + 802816);
    f16*   kp    = qp + (size_t)BATCH * SEQL * 256;
    f16*   vp    = kp + (size_t)BATCH * SEQL * 256;

    prep_kernel<<<1025, 256, 0, stream>>>(Wq, Wk, Wv, Wm, bq, bk, bv, w16, bperm);
    zero_kernel<<<(65536 + 2048 + 255) / 256, 256, 0, stream>>>(KV, 65536 + 2048);

    gemm_stage1<<<dim3(SEQL / 128, 4, 24), 256, 0, stream>>>(
        query, key_, value, w16, bperm, qp, kp, vp);

    kv_kernel<<<dim3(16, BATCH * NHEADS), 256, 0, stream>>>(kp, vp, KV, ksum);

    attn_out_kernel<<<dim3(SEQL / 64, BATCH), 256, 0, stream>>>(
        qp, KV, ksum, w16 + 3 * 65536, bm, (float*)d_out);
}

// Round 5
// 221.807 us; speedup vs baseline: 1.1021x; 1.1021x over previous
//
#include <hip/hip_runtime.h>
#include <math.h>

#define D_MODEL 256
#define NHEADS 8
#define HDIM 32
#define BATCH 8
#define SEQL 4096
#define EPS 1e-6f

typedef _Float16 f16;
typedef _Float16 f16x4 __attribute__((ext_vector_type(4)));
typedef _Float16 f16x8 __attribute__((ext_vector_type(8)));
typedef float f32x4 __attribute__((ext_vector_type(4)));

__device__ __forceinline__ float elu1(float x) {
    return x > 0.f ? x + 1.f : __expf(x);
}

// ---------------------------------------------------------------------------
// prep: convert 4 weight mats to fp16 (stage-1 rows permuted to head-major
// o' = h*32+kd; Wm columns permuted to match), permute stage-1 biases, and
// zero the KV/ksum accumulators (blocks 1025+).
// ---------------------------------------------------------------------------
__global__ void prep_kernel(const float* __restrict__ Wq, const float* __restrict__ Wk,
                            const float* __restrict__ Wv, const float* __restrict__ Wm,
                            const float* __restrict__ bq, const float* __restrict__ bk,
                            const float* __restrict__ bv,
                            f16* __restrict__ w16, float* __restrict__ bperm,
                            float* __restrict__ KVz) {
    const int bid = blockIdx.x;
    if (bid < 1024) {
        int idx = bid * 256 + threadIdx.x;
        int mat = idx >> 16, r = (idx >> 8) & 255, c = idx & 255;
        const float* W = (mat == 0) ? Wq : (mat == 1) ? Wk : (mat == 2) ? Wv : Wm;
        float v;
        if (mat < 3) v = W[(size_t)(((r & 31) << 3) + (r >> 5)) * 256 + c];
        else         v = W[(size_t)r * 256 + (((c & 31) << 3) + (c >> 5))];
        w16[idx] = (f16)v;
    } else if (bid == 1024) {
        int t = threadIdx.x;
        bperm[0 * 256 + t] = bq[((t & 31) << 3) + (t >> 5)];
        bperm[1 * 256 + t] = bk[((t & 31) << 3) + (t >> 5)];
        bperm[2 * 256 + t] = bv[((t & 31) << 3) + (t >> 5)];
    } else {
        int i = (bid - 1025) * 256 + threadIdx.x;  // 264 blocks * 256 = 67584
        KVz[i] = 0.f;
    }
}

// ---------------------------------------------------------------------------
// Stage-1 GEMM: Y[b][l][o'] = fp16( sum_i W16[o'][i] * X[b][i][l] + bperm[o'] )
// 128x128 tile (16 MFMA/wave/iter).  LDS = Bs only (40-half rows, 2-way max).
// W fragments direct from global (L2-hot) with one-iter register ping-pong;
// X float4s register-prefetched one iter ahead.  2 barriers/iter.
// ---------------------------------------------------------------------------
#define BSTR 40
__global__ __launch_bounds__(256, 3) void gemm_stage1(
    const float* __restrict__ Xq, const float* __restrict__ Xk, const float* __restrict__ Xv,
    const f16* __restrict__ w16, const float* __restrict__ bperm,
    f16* __restrict__ yq, f16* __restrict__ yk, f16* __restrict__ yv) {
    __shared__ __align__(16) char smem[18432];
    f16* Bs = (f16*)smem;   // [128][BSTR] = 10240 B
    f16* Cb = (f16*)smem;   // [128][72] epilogue bounce (aliases Bs)

    const int z = blockIdx.z;
    const int which = z >> 3;
    const int b = z & 7;
    const float* X = (which == 0) ? Xq : (which == 1) ? Xk : Xv;
    const f16* W = w16 + which * 65536;
    f16* Y = (which == 0) ? yq : (which == 1) ? yk : yv;
    const float* bp = bperm + which * 256;

    const int l0 = blockIdx.x * 128;
    const int m0 = blockIdx.y * 128;
    const int tid = threadIdx.x;
    const int wave = tid >> 6, lane = tid & 63;
    const int wm = wave >> 1, wn = wave & 1;
    const int ln = lane & 15, quad = lane >> 4;
    const int bp8 = tid & 7;    // i-quad: i_local = 4*bp8 + r
    const int bg = tid >> 3;    // l-quad: l_local = 4*bg + j

    const float* Xbase = X + ((size_t)b * D_MODEL + 4 * bp8) * SEQL + l0 + 4 * bg;
    const f16* Wb[4];
#pragma unroll
    for (int mf = 0; mf < 4; ++mf)
        Wb[mf] = W + (size_t)(m0 + wm * 64 + mf * 16 + ln) * 256 + quad * 8;

    float4 xr[4];
    f16x8 afc[4], afn[4];

#define LOADX(K0) do { \
        const float* xb_ = Xbase + (size_t)(K0) * SEQL; \
        xr[0] = *(const float4*)(xb_ + 0 * SEQL); \
        xr[1] = *(const float4*)(xb_ + 1 * SEQL); \
        xr[2] = *(const float4*)(xb_ + 2 * SEQL); \
        xr[3] = *(const float4*)(xb_ + 3 * SEQL); \
    } while (0)

#define STOREB() do { \
        f16x4 w_; \
        w_[0] = (f16)xr[0].x; w_[1] = (f16)xr[1].x; w_[2] = (f16)xr[2].x; w_[3] = (f16)xr[3].x; \
        *(f16x4*)&Bs[(4 * bg + 0) * BSTR + 4 * bp8] = w_; \
        w_[0] = (f16)xr[0].y; w_[1] = (f16)xr[1].y; w_[2] = (f16)xr[2].y; w_[3] = (f16)xr[3].y; \
        *(f16x4*)&Bs[(4 * bg + 1) * BSTR + 4 * bp8] = w_; \
        w_[0] = (f16)xr[0].z; w_[1] = (f16)xr[1].z; w_[2] = (f16)xr[2].z; w_[3] = (f16)xr[3].z; \
        *(f16x4*)&Bs[(4 * bg + 2) * BSTR + 4 * bp8] = w_; \
        w_[0] = (f16)xr[0].w; w_[1] = (f16)xr[1].w; w_[2] = (f16)xr[2].w; w_[3] = (f16)xr[3].w; \
        *(f16x4*)&Bs[(4 * bg + 3) * BSTR + 4 * bp8] = w_; \
    } while (0)

    f32x4 acc[4][4];
#pragma unroll
    for (int mf = 0; mf < 4; ++mf)
#pragma unroll
        for (int nf = 0; nf < 4; ++nf)
#pragma unroll
            for (int r = 0; r < 4; ++r) acc[mf][nf][r] = 0.f;

    // prologue
    LOADX(0);
#pragma unroll
    for (int mf = 0; mf < 4; ++mf) afc[mf] = *(const f16x8*)(Wb[mf] + 0);

#pragma unroll
    for (int it = 0; it < 8; ++it) {
        const int k0 = it * 32;
        __syncthreads();   // Bs free (prev compute done)
        STOREB();          // xr loaded last iter -> LDS
        __syncthreads();   // Bs ready
        if (it < 7) {
            LOADX(k0 + 32);  // next X in flight across compute
#pragma unroll
            for (int mf = 0; mf < 4; ++mf)
                afn[mf] = *(const f16x8*)(Wb[mf] + k0 + 32);
        }
        f16x8 bf[4];
#pragma unroll
        for (int nf = 0; nf < 4; ++nf)
            bf[nf] = *(const f16x8*)&Bs[(wn * 64 + nf * 16 + ln) * BSTR + quad * 8];
#pragma unroll
        for (int mf = 0; mf < 4; ++mf)
#pragma unroll
            for (int nf = 0; nf < 4; ++nf)
                acc[mf][nf] = __builtin_amdgcn_mfma_f32_16x16x32_f16(afc[mf], bf[nf], acc[mf][nf], 0, 0, 0);
#pragma unroll
        for (int mf = 0; mf < 4; ++mf) afc[mf] = afn[mf];
    }

    // epilogue: bias, bounce through LDS as [l][o], coalesced fp16 store
    float bv_[4][4];
#pragma unroll
    for (int mf = 0; mf < 4; ++mf)
#pragma unroll
        for (int r = 0; r < 4; ++r)
            bv_[mf][r] = bp[m0 + wm * 64 + mf * 16 + quad * 4 + r];
#pragma unroll
    for (int pass = 0; pass < 2; ++pass) {
        __syncthreads();
        if (wm == pass) {
#pragma unroll
            for (int mf = 0; mf < 4; ++mf)
#pragma unroll
                for (int nf = 0; nf < 4; ++nf) {
                    const int olocal = mf * 16 + quad * 4;
                    const int llocal = wn * 64 + nf * 16 + ln;
                    f16x4 w;
#pragma unroll
                    for (int r = 0; r < 4; ++r) w[r] = (f16)(acc[mf][nf][r] + bv_[mf][r]);
                    *(f16x4*)&Cb[llocal * 72 + olocal] = w;
                }
        }
        __syncthreads();
        const int l = tid >> 1, half = tid & 1;
        f16* yr = Y + ((size_t)(b * SEQL + l0 + l)) * 256 + m0 + pass * 64 + half * 32;
#pragma unroll
        for (int u = 0; u < 4; ++u)
            *(f16x8*)(yr + u * 8) = *(const f16x8*)&Cb[l * 72 + half * 32 + u * 8];
    }
}

// ---------------------------------------------------------------------------
// KV[b][h][qd][kd] = sum_l elu1(k'[l][kd]) * v'[l][qd];  ksum likewise.
// inputs fp16 [b][l][h*32+d].  grid (16 splits, 64 bh), 256 threads.
// ---------------------------------------------------------------------------
__global__ __launch_bounds__(256) void kv_kernel(
    const f16* __restrict__ kp, const f16* __restrict__ vp,
    float* __restrict__ KV, float* __restrict__ ksum) {
    const int bh = blockIdx.y;
    const int b = bh >> 3, h = bh & 7;
    const int lbase = blockIdx.x * (SEQL / 16);
    __shared__ float ks[64][33];
    __shared__ float vs[64][33];
    const int t = threadIdx.x;
    const int lrow = t >> 2, seg = t & 3;
    const int kd = t & 31, qg = t >> 5;
    float a0 = 0.f, a1 = 0.f, a2 = 0.f, a3 = 0.f, ss = 0.f;
    for (int lc = 0; lc < SEQL / 16; lc += 64) {
        __syncthreads();
        const size_t off = ((size_t)(b * SEQL + lbase + lc + lrow)) * 256 + h * 32 + seg * 8;
        f16x8 k8 = *(const f16x8*)(kp + off);
        f16x8 v8 = *(const f16x8*)(vp + off);
#pragma unroll
        for (int j = 0; j < 8; ++j) {
            ks[lrow][seg * 8 + j] = elu1((float)k8[j]);
            vs[lrow][seg * 8 + j] = (float)v8[j];
        }
        __syncthreads();
#pragma unroll 8
        for (int li = 0; li < 64; ++li) {
            const float kk = ks[li][kd];
            ss += kk;
            a0 += kk * vs[li][qg * 4 + 0];
            a1 += kk * vs[li][qg * 4 + 1];
            a2 += kk * vs[li][qg * 4 + 2];
            a3 += kk * vs[li][qg * 4 + 3];
        }
    }
    float* KVb = KV + (size_t)(b * NHEADS + h) * HDIM * HDIM;
    atomicAdd(&KVb[(qg * 4 + 0) * HDIM + kd], a0);
    atomicAdd(&KVb[(qg * 4 + 1) * HDIM + kd], a1);
    atomicAdd(&KVb[(qg * 4 + 2) * HDIM + kd], a2);
    atomicAdd(&KVb[(qg * 4 + 3) * HDIM + kd], a3);
    if (qg == 0) atomicAdd(&ksum[(size_t)(b * NHEADS + h) * HDIM + kd], ss);
}

// ---------------------------------------------------------------------------
// Fused attention + output projection; phase2 Wm frags now register ping-pong
// prefetched (L2 latency off the critical path).
// ---------------------------------------------------------------------------
__global__ __launch_bounds__(256) void attn_out_kernel(
    const f16* __restrict__ qp, const float* __restrict__ KV,
    const float* __restrict__ ksum, const f16* __restrict__ wm16,
    const float* __restrict__ bm, float* __restrict__ out) {
    __shared__ __align__(16) f16 xs[64 * 264];        // 33792 B
    __shared__ __align__(16) f16 Baug[8 * 48 * 40];   // 30720 B
    __shared__ float dens[8][64];                     // 2048 B
    const int b = blockIdx.y;
    const int l0 = blockIdx.x * 64;
    const int t = threadIdx.x;
    const int wave = t >> 6, lane = t & 63;
    const int ln = lane & 15, quad = lane >> 4;

    {
        const int h = t >> 5, qd = t & 31;
        const float* kvp = KV + ((size_t)(b * NHEADS + h) * HDIM + qd) * HDIM;
        f16* dst = &Baug[(h * 48 + qd) * 40];
#pragma unroll
        for (int i = 0; i < 32; i += 4) {
            float4 a = *(const float4*)(kvp + i);
            f16x4 w4;
            w4[0] = (f16)a.x; w4[1] = (f16)a.y; w4[2] = (f16)a.z; w4[3] = (f16)a.w;
            *(f16x4*)(dst + i) = w4;
        }
        Baug[(h * 48 + 32) * 40 + qd] = (f16)ksum[(size_t)(b * NHEADS + h) * HDIM + qd];
    }
    {
        const int row = t & 63, cg = t >> 6;
        const f16* qr = qp + ((size_t)(b * SEQL + l0 + row)) * 256 + cg * 64;
        f16* dst = &xs[row * 264 + cg * 64];
#pragma unroll
        for (int u = 0; u < 64; u += 8) {
            f16x8 v = *(const f16x8*)(qr + u);
            f16x8 w;
#pragma unroll
            for (int j = 0; j < 8; ++j) w[j] = (f16)elu1((float)v[j]);
            *(f16x8*)(dst + u) = w;
        }
    }
    __syncthreads();
#pragma unroll
    for (int hh = 0; hh < 2; ++hh) {
        const int h = wave * 2 + hh;
        f16x8 a_s[4], b_s[3];
#pragma unroll
        for (int mf = 0; mf < 4; ++mf)
            a_s[mf] = *(const f16x8*)&xs[(mf * 16 + ln) * 264 + h * 32 + quad * 8];
#pragma unroll
        for (int nf = 0; nf < 3; ++nf)
            b_s[nf] = *(const f16x8*)&Baug[(h * 48 + nf * 16 + ln) * 40 + quad * 8];
        f32x4 C[4][3];
#pragma unroll
        for (int mf = 0; mf < 4; ++mf)
#pragma unroll
            for (int nf = 0; nf < 3; ++nf) {
#pragma unroll
                for (int r = 0; r < 4; ++r) C[mf][nf][r] = 0.f;
                C[mf][nf] = __builtin_amdgcn_mfma_f32_16x16x32_f16(a_s[mf], b_s[nf], C[mf][nf], 0, 0, 0);
            }
        if (ln == 0) {
#pragma unroll
            for (int mf = 0; mf < 4; ++mf)
#pragma unroll
                for (int r = 0; r < 4; ++r)
                    dens[h][mf * 16 + quad * 4 + r] = C[mf][2][r];
        }
        __syncthreads();
#pragma unroll
        for (int mf = 0; mf < 4; ++mf)
#pragma unroll
            for (int r = 0; r < 4; ++r) {
                const int l = mf * 16 + quad * 4 + r;
                const float rd = __builtin_amdgcn_rcpf(dens[h][l] + EPS);
#pragma unroll
                for (int nf = 0; nf < 2; ++nf)
                    xs[l * 264 + h * 32 + nf * 16 + ln] = (f16)(C[mf][nf][r] * rd);
            }
        __syncthreads();
    }
    // phase2: main GEMM, A = Wm prefetched ping-pong from global, B = xs
    f32x4 acc[4][4];
#pragma unroll
    for (int mf = 0; mf < 4; ++mf)
#pragma unroll
        for (int nf = 0; nf < 4; ++nf)
#pragma unroll
            for (int r = 0; r < 4; ++r) acc[mf][nf][r] = 0.f;
    const f16* Wb[4];
#pragma unroll
    for (int mf = 0; mf < 4; ++mf)
        Wb[mf] = wm16 + (size_t)(wave * 64 + mf * 16 + ln) * 256 + quad * 8;
    f16x8 afc[4], afn[4];
#pragma unroll
    for (int mf = 0; mf < 4; ++mf) afc[mf] = *(const f16x8*)(Wb[mf] + 0);
#pragma unroll
    for (int it = 0; it < 8; ++it) {
        const int k0 = it * 32;
        if (it < 7) {
#pragma unroll
            for (int mf = 0; mf < 4; ++mf) afn[mf] = *(const f16x8*)(Wb[mf] + k0 + 32);
        }
        f16x8 bf[4];
#pragma unroll
        for (int nf = 0; nf < 4; ++nf)
            bf[nf] = *(const f16x8*)&xs[(nf * 16 + ln) * 264 + k0 + quad * 8];
#pragma unroll
        for (int mf = 0; mf < 4; ++mf)
#pragma unroll
            for (int nf = 0; nf < 4; ++nf)
                acc[mf][nf] = __builtin_amdgcn_mfma_f32_16x16x32_f16(afc[mf], bf[nf], acc[mf][nf], 0, 0, 0);
#pragma unroll
        for (int mf = 0; mf < 4; ++mf) afc[mf] = afn[mf];
    }
#pragma unroll
    for (int mf = 0; mf < 4; ++mf) {
        const int o = wave * 64 + mf * 16 + quad * 4;
#pragma unroll
        for (int r = 0; r < 4; ++r) {
            const float bb = bm[o + r];
            float* op = out + ((size_t)(b * D_MODEL + o + r)) * SEQL + l0;
#pragma unroll
            for (int nf = 0; nf < 4; ++nf)
                op[nf * 16 + ln] = acc[mf][nf][r] + bb;
        }
    }
}

// ---------------------------------------------------------------------------
extern "C" void kernel_launch(void* const* d_in, const int* in_sizes, int n_in,
                              void* d_out, int out_size, void* d_ws, size_t ws_size,
                              hipStream_t stream) {
    const float* query = (const float*)d_in[0];
    const float* key_  = (const float*)d_in[1];
    const float* value = (const float*)d_in[2];
    const float* Wq = (const float*)d_in[3];
    const float* bq = (const float*)d_in[4];
    const float* Wk = (const float*)d_in[5];
    const float* bk = (const float*)d_in[6];
    const float* Wv = (const float*)d_in[7];
    const float* bv = (const float*)d_in[8];
    const float* Wm = (const float*)d_in[9];
    const float* bm = (const float*)d_in[10];

    char* w = (char*)d_ws;
    f16*   w16   = (f16*)w;                       // 4*65536 halves = 512 KB
    float* bperm = (float*)(w + 524288);          // 768 floats
    float* KV    = (float*)(w + 528384);          // 65536 floats (+2048 ksum, zeroed together)
    float* ksum  = (float*)(w + 790528);          // 2048 floats
    f16*   qp    = (f16*)(w + 802816);
    f16*   kp    = qp + (size_t)BATCH * SEQL * 256;
    f16*   vp    = kp + (size_t)BATCH * SEQL * 256;

    prep_kernel<<<1289, 256, 0, stream>>>(Wq, Wk, Wv, Wm, bq, bk, bv, w16, bperm, KV);

    gemm_stage1<<<dim3(SEQL / 128, 2, 24), 256, 0, stream>>>(
        query, key_, value, w16, bperm, qp, kp, vp);

    kv_kernel<<<dim3(16, BATCH * NHEADS), 256, 0, stream>>>(kp, vp, KV, ksum);

    attn_out_kernel<<<dim3(SEQL / 64, BATCH), 256, 0, stream>>>(
        qp, KV, ksum, w16 + 3 * 65536, bm, (float*)d_out);
}